// Round 1
// baseline (631.894 us; speedup 1.0000x reference)
//
#include <hip/hip_runtime.h>
#include <hip/hip_bf16.h>
#include <stdint.h>

typedef unsigned short u16;
typedef unsigned int   u32;
typedef __bf16 bf16x8 __attribute__((ext_vector_type(8)));
typedef float  f32x16 __attribute__((ext_vector_type(16)));

// ---------- bf16 helpers ----------
__device__ __forceinline__ u16 bf16_rn(float f) {
  union { float f; u32 u; } v; v.f = f;
  u32 u = v.u;
  u32 r = (u + 0x7FFFu + ((u >> 16) & 1u)) >> 16;   // round-to-nearest-even
  return (u16)r;
}
__device__ __forceinline__ float bf16_tof(u16 h) {
  union { u32 u; float f; } v; v.u = ((u32)h) << 16;
  return v.f;
}

__device__ __forceinline__ f32x16 MFMA(bf16x8 a, bf16x8 b, f32x16 c) {
  return __builtin_amdgcn_mfma_f32_32x32x16_bf16(a, b, c, 0, 0, 0);
}

// ---------- LDS layout (bytes). Total 130048 <= 128 KiB ----------
// Phase L1: X[0..41984) | Wbuf[41984..70656) | H1h[70656..100352) | H1l[100352..130048)
// Phase L2: H2h[0..17408) H2l[17408..34816) | Wbuf | H1 read
// Phase L3: H2 read | Wbuf | H3h[70656..79872) H3l[79872..89088)
// Phase L4: OUT f32 [0..8192) | Wbuf | H3 read
#define OFF_X    0
#define OFF_W    41984
#define OFF_H1H  70656
#define OFF_H1L  100352
#define OFF_H2H  0
#define OFF_H2L  17408
#define OFF_H3H  70656
#define OFF_H3L  79872
#define OFF_OUT  0
#define LDS_BYTES 130048

// ---------- weight prep: fp32 [N][K] -> bf16 hi/lo MFMA-B fragments ----------
// Per (kc16, nt32) block: 2048 B = [hi: 64 lanes x 16 B][lo: 64 lanes x 16 B]
// lane l holds col n = nt*32 + (l&31), k = kc*16 + (l>>5)*8 + j  (j=0..7)
// Block order within a layer: b = kc*NT + nt. Layer bases (blocks): L1=0, L2=140, L3=196, L4=212.
__global__ __launch_bounds__(64) void prep_kernel(
    const float* __restrict__ W1, const float* __restrict__ W2,
    const float* __restrict__ W3, const float* __restrict__ W4,
    u16* __restrict__ wf)
{
  int b = blockIdx.x;
  int lane = threadIdx.x;
  const float* W; int NT, rel, Nv, Kv;
  if (b < 140)      { W = W1; NT = 7; rel = b;       Nv = 200; Kv = 300; }
  else if (b < 196) { W = W2; NT = 4; rel = b - 140; Nv = 100; Kv = 200; }
  else if (b < 212) { W = W3; NT = 2; rel = b - 196; Nv = 50;  Kv = 100; }
  else              { W = W4; NT = 1; rel = b - 212; Nv = 10;  Kv = 50;  }
  int kc = rel / NT, nt = rel % NT;
  int n = nt * 32 + (lane & 31);
  int kbase = kc * 16 + ((lane >> 5) << 3);
  u16* dst = wf + (size_t)b * 1024;   // 2048 B per block
  #pragma unroll
  for (int j = 0; j < 8; ++j) {
    int k = kbase + j;
    float w = (n < Nv && k < Kv) ? W[n * Kv + k] : 0.0f;
    u16 h = bf16_rn(w);
    dst[lane * 8 + j]       = h;
    dst[512 + lane * 8 + j] = bf16_rn(w - bf16_tof(h));
  }
}

// ---------- generic fused layer ----------
// Wave wid: M-tiles 0,1 (rows 0-31 / 32-63), N-tiles [ (wid*NT)/4 , ((wid+1)*NT)/4 )
template<int NT, int KC, int STEPK, bool SPLIT_A, bool RELU, bool OUTF32>
__device__ __forceinline__ void layer_gemm(
    char* lds,
    int offAh, int offAl, int strideAu,      // A (activations) in LDS, ushort stride
    const char* wglob,                        // layer's fragment blocks in d_ws
    const float* __restrict__ bias, int nvalid,
    int offHh, int offHl, int strideHu,      // output in LDS
    int lane, int wid, int tid)
{
  constexpr int CHUNK = STEPK * NT * 2048;
  constexpr int NSTEP = KC / STEPK;
  constexpr int NLD = (CHUNK + 4095) / 4096;  // float4 slots per thread (256 thr x 16 B)
  const int nt0 = (wid * NT) >> 2;
  const int nNt = (((wid + 1) * NT) >> 2) - nt0;

  // prologue: stage chunk 0 into buf0
  {
    float4 r[NLD];
    #pragma unroll
    for (int it = 0; it < NLD; ++it) {
      int off = tid * 16 + it * 4096;
      if (off < CHUNK) r[it] = *(const float4*)(wglob + off);
    }
    #pragma unroll
    for (int it = 0; it < NLD; ++it) {
      int off = tid * 16 + it * 4096;
      if (off < CHUNK) *(float4*)(lds + OFF_W + off) = r[it];
    }
  }
  __syncthreads();

  f32x16 acc[2][2] = {};
  int cur = 0;
  for (int step = 0; step < NSTEP; ++step) {
    // T14: issue next chunk's global loads early
    float4 r[NLD];
    const bool have = (step + 1 < NSTEP);
    if (have) {
      const char* g = wglob + (size_t)(step + 1) * CHUNK;
      #pragma unroll
      for (int it = 0; it < NLD; ++it) {
        int off = tid * 16 + it * 4096;
        if (off < CHUNK) r[it] = *(const float4*)(g + off);
      }
    }
    // compute on buf[cur]
    #pragma unroll
    for (int kk = 0; kk < STEPK; ++kk) {
      const int kc = step * STEPK + kk;
      const int kbyte = (kc * 16 + ((lane >> 5) << 3)) * 2;
      const char* wb = lds + OFF_W + cur * CHUNK + kk * NT * 2048;
      bf16x8 ah[2], al[2];
      #pragma unroll
      for (int mt = 0; mt < 2; ++mt) {
        const int row = mt * 32 + (lane & 31);
        ah[mt] = *(const bf16x8*)(lds + offAh + row * (strideAu * 2) + kbyte);
        if constexpr (SPLIT_A)
          al[mt] = *(const bf16x8*)(lds + offAl + row * (strideAu * 2) + kbyte);
      }
      #pragma unroll
      for (int ni = 0; ni < 2; ++ni) {
        if (ni < nNt) {
          const char* blk = wb + (nt0 + ni) * 2048 + (size_t)lane * 16;
          bf16x8 bh = *(const bf16x8*)(blk);
          bf16x8 bl = *(const bf16x8*)(blk + 1024);
          #pragma unroll
          for (int mt = 0; mt < 2; ++mt) {
            acc[ni][mt] = MFMA(ah[mt], bh, acc[ni][mt]);
            acc[ni][mt] = MFMA(ah[mt], bl, acc[ni][mt]);
            if constexpr (SPLIT_A)
              acc[ni][mt] = MFMA(al[mt], bh, acc[ni][mt]);
          }
        }
      }
    }
    // write staged chunk into the other buffer
    if (have) {
      asm volatile("s_waitcnt vmcnt(0)" ::: "memory");
      char* dst = lds + OFF_W + (cur ^ 1) * CHUNK;
      #pragma unroll
      for (int it = 0; it < NLD; ++it) {
        int off = tid * 16 + it * 4096;
        if (off < CHUNK) *(float4*)(dst + off) = r[it];
      }
    }
    __syncthreads();
    cur ^= 1;
  }

  // epilogue: bias (+relu) -> split bf16 (or f32) into LDS
  #pragma unroll
  for (int ni = 0; ni < 2; ++ni) {
    if (ni < nNt) {
      const int col = (nt0 + ni) * 32 + (lane & 31);
      const float bv = (col < nvalid) ? bias[col] : 0.0f;
      #pragma unroll
      for (int mt = 0; mt < 2; ++mt) {
        #pragma unroll
        for (int rg = 0; rg < 16; ++rg) {
          const int row = mt * 32 + (rg & 3) + ((rg >> 2) << 3) + (((lane >> 5) & 1) << 2);
          float v = acc[ni][mt][rg] + bv;
          if constexpr (RELU) v = fmaxf(v, 0.0f);
          if constexpr (OUTF32) {
            *(float*)(lds + offHh + (row * strideHu + col) * 4) = v;
          } else {
            u16 h = bf16_rn(v);
            *(u16*)(lds + offHh + ((size_t)row * strideHu + col) * 2) = h;
            *(u16*)(lds + offHl + ((size_t)row * strideHu + col) * 2) = bf16_rn(v - bf16_tof(h));
          }
        }
      }
    }
  }
  __syncthreads();
}

// ---------- quantum epilogue ----------
struct cpx { float r, i; };
__device__ __forceinline__ void ry_pair(float c, float s, cpx& a, cpx& b) {
  cpx na = { c * a.r - s * b.r, c * a.i - s * b.i };
  cpx nb = { s * a.r + c * b.r, s * a.i + c * b.i };
  a = na; b = nb;
}
__device__ __forceinline__ void rx_pair(float c, float s, cpx& a, cpx& b) {
  // (a,b) -> (c*a - i*s*b, -i*s*a + c*b)
  cpx na = { c * a.r + s * b.i, c * a.i - s * b.r };
  cpx nb = { s * a.i + c * b.r, -s * a.r + c * b.i };
  a = na; b = nb;
}
// v = U(p[5..9]) @ ( first(p[1]) @ second(p[2],p[3]) @ e0 )   [crx@e0 = e0]
__device__ void build_state(const float* p, cpx v[4]) {
  float a1 = 0.5f * p[1], a2 = 0.5f * p[2], a3 = 0.5f * p[3];
  float c2 = cosf(a2), s2 = sinf(a2), c3 = cosf(a3), s3 = sinf(a3);
  v[0] = { c2 * c3, 0.f }; v[1] = { c2 * s3, 0.f };
  v[2] = { s2 * c3, 0.f }; v[3] = { s2 * s3, 0.f };
  float c1 = cosf(a1), s1 = sinf(a1);
  rx_pair(c1, s1, v[0], v[1]); rx_pair(c1, s1, v[2], v[3]);  // Rx(p1) qubit2
  rx_pair(c1, s1, v[0], v[2]); rx_pair(c1, s1, v[1], v[3]);  // Rx(p1) qubit1
  // apply U(q): crx(q4), then kron(ry(q2), ry(q3)), then kron(rx(q1), rx(q1))
  float q1 = 0.5f * p[6], q2 = 0.5f * p[7], q3 = 0.5f * p[8], q4 = 0.5f * p[9];
  float c4 = cosf(q4), s4 = sinf(q4);
  rx_pair(c4, s4, v[1], v[3]);                                // CRx: control qubit2
  float cc = cosf(q3), ss = sinf(q3);
  ry_pair(cc, ss, v[0], v[1]); ry_pair(cc, ss, v[2], v[3]);   // Ry(q3) qubit2
  cc = cosf(q2); ss = sinf(q2);
  ry_pair(cc, ss, v[0], v[2]); ry_pair(cc, ss, v[1], v[3]);   // Ry(q2) qubit1
  cc = cosf(q1); ss = sinf(q1);
  rx_pair(cc, ss, v[0], v[1]); rx_pair(cc, ss, v[2], v[3]);   // Rx(q1) both
  rx_pair(cc, ss, v[0], v[2]); rx_pair(cc, ss, v[1], v[3]);
}

// ---------- fused kernel: 64 rows of [2B,300] per WG ----------
__global__ __launch_bounds__(256, 1) void fused_kernel(
    const float* __restrict__ X,
    const float* __restrict__ b1, const float* __restrict__ b2,
    const float* __restrict__ b3, const float* __restrict__ b4,
    const u16* __restrict__ wf,
    float* __restrict__ out)
{
  __shared__ float4 ldsv[LDS_BYTES / 16];
  char* lds = (char*)ldsv;
  const int tid  = threadIdx.x;
  const int lane = tid & 63;
  const int wid  = tid >> 6;
  const int wg   = blockIdx.x;

  // Phase X: 64 rows x 300 fp32 -> bf16 into LDS [64][328] (cols 300..327 zero)
  {
    const float4* xb = (const float4*)(X + (size_t)wg * 64 * 300);
    u16* Xl = (u16*)(lds + OFF_X);
    for (int t = tid; t < 4800; t += 256) {
      float4 f = xb[t];
      int row = t / 75;
      int c4  = (t - row * 75) * 4;
      ushort4 pk = make_ushort4(bf16_rn(f.x), bf16_rn(f.y), bf16_rn(f.z), bf16_rn(f.w));
      *(ushort4*)&Xl[row * 328 + c4] = pk;
    }
    for (int t = tid; t < 64 * 28; t += 256) {
      int row = t / 28, c = 300 + (t - row * 28);
      Xl[row * 328 + c] = 0;
    }
  }
  __syncthreads();

  // L1: K=320(20kc), N=224(7nt), A = X (hi only)
  layer_gemm<7, 20, 1, false, true, false>(lds, OFF_X, 0, 328,
      (const char*)wf, b1, 200, OFF_H1H, OFF_H1L, 232, lane, wid, tid);
  // L2: K=224(14kc), N=128(4nt), A = H1 hi+lo
  layer_gemm<4, 14, 1, true, true, false>(lds, OFF_H1H, OFF_H1L, 232,
      (const char*)wf + 140 * 2048, b2, 100, OFF_H2H, OFF_H2L, 136, lane, wid, tid);
  // L3: K=128(8kc), N=64(2nt)
  layer_gemm<2, 8, 2, true, true, false>(lds, OFF_H2H, OFF_H2L, 136,
      (const char*)wf + 196 * 2048, b3, 50, OFF_H3H, OFF_H3L, 72, lane, wid, tid);
  // L4: K=64(4kc), N=32(1nt), f32 out, no relu
  layer_gemm<1, 4, 4, true, false, true>(lds, OFF_H3H, OFF_H3L, 72,
      (const char*)wf + 212 * 2048, b4, 10, OFF_OUT, 0, 32, lane, wid, tid);

  // quantum epilogue: 32 batch elements per WG (rows 2t, 2t+1)
  if (tid < 32) {
    const float* O = (const float*)(lds + OFF_OUT);
    float p1[10], p2[10];
    #pragma unroll
    for (int j = 0; j < 10; ++j) {
      p1[j] = O[(2 * tid) * 32 + j];
      p2[j] = O[(2 * tid + 1) * 32 + j];
    }
    cpx v[4], w[4];
    build_state(p1, v);   // ket side from l1
    build_state(p2, w);   // bra side from l2
    float ir = 0.f, ii = 0.f;
    #pragma unroll
    for (int k = 0; k < 4; ++k) {
      ir += w[k].r * v[k].r + w[k].i * v[k].i;   // conj(w) . v
      ii += w[k].r * v[k].i - w[k].i * v[k].r;
    }
    out[wg * 32 + tid] = ir * ir + ii * ii;
  }
}

extern "C" void kernel_launch(void* const* d_in, const int* in_sizes, int n_in,
                              void* d_out, int out_size, void* d_ws, size_t ws_size,
                              hipStream_t stream)
{
  const float* X  = (const float*)d_in[0];
  const float* W1 = (const float*)d_in[1];
  const float* b1 = (const float*)d_in[2];
  const float* W2 = (const float*)d_in[3];
  const float* b2 = (const float*)d_in[4];
  const float* W3 = (const float*)d_in[5];
  const float* b3 = (const float*)d_in[6];
  const float* W4 = (const float*)d_in[7];
  const float* b4 = (const float*)d_in[8];
  u16* wf = (u16*)d_ws;   // 216 blocks * 2048 B = 442368 B of scratch

  prep_kernel<<<dim3(216), dim3(64), 0, stream>>>(W1, W2, W3, W4, wf);
  fused_kernel<<<dim3(2048), dim3(256), 0, stream>>>(X, b1, b2, b3, b4, wf, (float*)d_out);
}

// Round 2
// 356.184 us; speedup vs baseline: 1.7741x; 1.7741x over previous
//
#include <hip/hip_runtime.h>
#include <hip/hip_bf16.h>
#include <stdint.h>

typedef unsigned short u16;
typedef unsigned int   u32;
typedef __bf16 bf16x8 __attribute__((ext_vector_type(8)));
typedef float  f32x16 __attribute__((ext_vector_type(16)));

__device__ __forceinline__ u16 b2u(__bf16 b){ union U{__bf16 b; u16 u;} v; v.b=b; return v.u; }

__device__ __forceinline__ f32x16 MFMA(bf16x8 a, bf16x8 b, f32x16 c) {
  return __builtin_amdgcn_mfma_f32_32x32x16_bf16(a, b, c, 0, 0, 0);
}

// ---- LDS geometry ----
// [0,32768): per-wave transpose scratch, 4 KB x 8 waves
// [32768,75776): weight buffer A (43008 B)   [75776,118784): weight buffer B
#define OFF_WA  32768
#define OFF_WB  75776
#define LDS_BYTES 118784

constexpr int CH1 = 43008;   // 3 kc * 7 nt * 2048 B
constexpr int CH2 = 32768;   // 4 kc * 4 nt * 2048
constexpr int CH3 = 16384;   // 4 kc * 2 nt * 2048
constexpr int CH4 = 8192;    // 4 kc * 1 nt * 2048
constexpr long B1 = 0;                 // L1: 21 kc x 7 nt = 147 blocks
constexpr long B2 = 147L * 2048;       // L2: 16 kc x 4 nt = 64 blocks
constexpr long B3 = 211L * 2048;       // L3:  8 kc x 2 nt = 16 blocks
constexpr long B4 = 227L * 2048;       // L4:  4 kc x 1 nt = 4 blocks  (231 total)

// ---- weight prep: fp32 [N][K] -> bf16 hi/lo MFMA-B fragment blocks ----
// block b = (kc, nt): 2048 B = [hi: 64 lanes x 16 B][lo: 64 lanes x 16 B]
// lane l: col n = nt*32 + (l&31), k = kc*16 + (l>>5)*8 + j
__global__ __launch_bounds__(64) void prep_kernel(
    const float* __restrict__ W1, const float* __restrict__ W2,
    const float* __restrict__ W3, const float* __restrict__ W4,
    u16* __restrict__ wf)
{
  int b = blockIdx.x, lane = threadIdx.x;
  const float* W; int NT, rel, Nv, Kv;
  if (b < 147)      { W = W1; NT = 7; rel = b;       Nv = 200; Kv = 300; }
  else if (b < 211) { W = W2; NT = 4; rel = b - 147; Nv = 100; Kv = 200; }
  else if (b < 227) { W = W3; NT = 2; rel = b - 211; Nv = 50;  Kv = 100; }
  else              { W = W4; NT = 1; rel = b - 227; Nv = 10;  Kv = 50;  }
  int kc = rel / NT, nt = rel % NT;
  int n  = nt*32 + (lane & 31);
  int kb = kc*16 + ((lane >> 5) << 3);
  u16* dst = wf + (size_t)b * 1024;
  #pragma unroll
  for (int j = 0; j < 8; ++j) {
    int k = kb + j;
    float w = (n < Nv && k < Kv) ? W[n*Kv + k] : 0.0f;
    __bf16 h = (__bf16)w;
    __bf16 l = (__bf16)(w - (float)h);
    dst[lane*8 + j]       = b2u(h);
    dst[512 + lane*8 + j] = b2u(l);
  }
}

// ---- T14 staging: issue loads early, write LDS after compute ----
template<int CHUNK>
__device__ __forceinline__ void stage_load(const char* __restrict__ g, float4* r, int tid) {
  constexpr int NS = (CHUNK + 8191) / 8192;
  #pragma unroll
  for (int it = 0; it < NS; ++it) {
    const int off = tid*16 + it*8192;
    if ((it+1)*8192 <= CHUNK)  r[it] = *(const float4*)(g + off);
    else if (off < CHUNK)      r[it] = *(const float4*)(g + off);
  }
}
template<int CHUNK>
__device__ __forceinline__ void stage_write(char* lds, const float4* r, int tid) {
  constexpr int NS = (CHUNK + 8191) / 8192;
  #pragma unroll
  for (int it = 0; it < NS; ++it) {
    const int off = tid*16 + it*8192;
    if ((it+1)*8192 <= CHUNK)  *(float4*)(lds + off) = r[it];
    else if (off < CHUNK)      *(float4*)(lds + off) = r[it];
  }
}
#define VMCNT0 asm volatile("s_waitcnt vmcnt(0)" ::: "memory")

// ---- layer transition: acc (C-layout) -> bias/relu -> hi/lo A-fragments ----
// wave-private scratch ms: hi plane [32 rows][64 B] at +0, lo plane at +2048,
// 2-bit XOR swizzle on 16 B groups within a row.
template<int NTILES>
__device__ __forceinline__ void transition(
    const f32x16* acc, const float* __restrict__ bias, int nvalid,
    bf16x8* hh, bf16x8* hl, char* ms, int lane)
{
  #pragma unroll
  for (int j = 0; j < NTILES; ++j) {
    const int col = j*32 + (lane & 31);
    const float bv = (col < nvalid) ? bias[col] : 0.0f;
    #pragma unroll
    for (int r = 0; r < 16; ++r) {
      const int row = (r & 3) + ((r >> 2) << 3) + (((lane >> 5) & 1) << 2);
      float v = fmaxf(acc[j][r] + bv, 0.0f);
      __bf16 h = (__bf16)v;
      __bf16 l = (__bf16)(v - (float)h);
      const int bo = row*64 + (((lane & 31) << 1) ^ ((row & 3) << 4));
      *(u16*)(ms + bo)        = b2u(h);
      *(u16*)(ms + 2048 + bo) = b2u(l);
    }
    #pragma unroll
    for (int h2 = 0; h2 < 2; ++h2) {
      const int row = lane & 31;
      const int bo = row*64 + ((h2*32 + ((lane >> 5) << 4)) ^ ((row & 3) << 4));
      hh[2*j + h2] = *(const bf16x8*)(ms + bo);
      hl[2*j + h2] = *(const bf16x8*)(ms + 2048 + bo);
    }
  }
}

// ---- quantum epilogue (verified in round 1) ----
struct cpx { float r, i; };
__device__ __forceinline__ void ry_pair(float c, float s, cpx& a, cpx& b) {
  cpx na = { c*a.r - s*b.r, c*a.i - s*b.i };
  cpx nb = { s*a.r + c*b.r, s*a.i + c*b.i };
  a = na; b = nb;
}
__device__ __forceinline__ void rx_pair(float c, float s, cpx& a, cpx& b) {
  cpx na = { c*a.r + s*b.i, c*a.i - s*b.r };
  cpx nb = { s*a.i + c*b.r, -s*a.r + c*b.i };
  a = na; b = nb;
}
__device__ void build_state(const float* p, cpx v[4]) {
  float a1 = 0.5f*p[1], a2 = 0.5f*p[2], a3 = 0.5f*p[3];
  float c2 = cosf(a2), s2 = sinf(a2), c3 = cosf(a3), s3 = sinf(a3);
  v[0] = { c2*c3, 0.f }; v[1] = { c2*s3, 0.f };
  v[2] = { s2*c3, 0.f }; v[3] = { s2*s3, 0.f };
  float c1 = cosf(a1), s1 = sinf(a1);
  rx_pair(c1, s1, v[0], v[1]); rx_pair(c1, s1, v[2], v[3]);
  rx_pair(c1, s1, v[0], v[2]); rx_pair(c1, s1, v[1], v[3]);
  float q1 = 0.5f*p[6], q2 = 0.5f*p[7], q3 = 0.5f*p[8], q4 = 0.5f*p[9];
  float c4 = cosf(q4), s4 = sinf(q4);
  rx_pair(c4, s4, v[1], v[3]);
  float cc = cosf(q3), ss = sinf(q3);
  ry_pair(cc, ss, v[0], v[1]); ry_pair(cc, ss, v[2], v[3]);
  cc = cosf(q2); ss = sinf(q2);
  ry_pair(cc, ss, v[0], v[2]); ry_pair(cc, ss, v[1], v[3]);
  cc = cosf(q1); ss = sinf(q1);
  rx_pair(cc, ss, v[0], v[1]); rx_pair(cc, ss, v[2], v[3]);
  rx_pair(cc, ss, v[0], v[2]); rx_pair(cc, ss, v[1], v[3]);
}

// ---- fused kernel: 8 waves x 32 rows = 256 rows of [2B,300] per WG ----
__global__ __launch_bounds__(512, 2) void fused_kernel(
    const float* __restrict__ X,
    const float* __restrict__ b1p, const float* __restrict__ b2p,
    const float* __restrict__ b3p, const float* __restrict__ b4p,
    const u16* __restrict__ wf,
    float* __restrict__ out)
{
  __shared__ char lds[LDS_BYTES] __attribute__((aligned(16)));
  const int tid  = threadIdx.x;
  const int lane = tid & 63;
  const int wid  = tid >> 6;
  const long rowbase = (long)blockIdx.x*256 + wid*32;
  char* ms = lds + wid*4096;
  const char* wfc = (const char*)wf;

  // prologue: issue L1-chunk0 stage, preload X as bf16 A-fragments (K=304 eff.)
  float4 s0[6];
  stage_load<CH1>(wfc + B1, s0, tid);

  bf16x8 xf[19];
  {
    const float* xp = X + (rowbase + (lane & 31))*300 + ((lane >> 5) << 3);
    #pragma unroll
    for (int kc = 0; kc < 19; ++kc) {
      float4 f0 = *(const float4*)(xp + kc*16);
      float4 f1;
      if (kc == 18) {   // k=296..303: upper half's 300..303 would be OOB -> zero (weights are 0 there)
        if (lane >= 32) f1 = make_float4(0.f, 0.f, 0.f, 0.f);
        else            f1 = *(const float4*)(xp + kc*16 + 4);
      } else {
        f1 = *(const float4*)(xp + kc*16 + 4);
      }
      xf[kc][0]=(__bf16)f0.x; xf[kc][1]=(__bf16)f0.y; xf[kc][2]=(__bf16)f0.z; xf[kc][3]=(__bf16)f0.w;
      xf[kc][4]=(__bf16)f1.x; xf[kc][5]=(__bf16)f1.y; xf[kc][6]=(__bf16)f1.z; xf[kc][7]=(__bf16)f1.w;
    }
  }
  VMCNT0;
  stage_write<CH1>(lds + OFF_WA, s0, tid);
  __syncthreads();

  // ---- L1: K=19 kc, N=224 (7 nt), A=xf (hi only), 2 MFMA/(kc,nt) ----
  f32x16 acc1[7] = {};
  #pragma unroll
  for (int step = 0; step < 7; ++step) {
    float4 sr[6];
    if (step < 6) stage_load<CH1>(wfc + B1 + (size_t)(step+1)*CH1, sr, tid);
    const char* wb = lds + ((step & 1) ? OFF_WB : OFF_WA);
    #pragma unroll
    for (int kk = 0; kk < 3; ++kk) {
      const int kc = step*3 + kk;
      if (kc < 19) {
        const bf16x8 ah = xf[kc];
        #pragma unroll
        for (int nt = 0; nt < 7; ++nt) {
          const char* bp = wb + (kk*7 + nt)*2048 + lane*16;
          bf16x8 bh = *(const bf16x8*)bp;
          bf16x8 bl = *(const bf16x8*)(bp + 1024);
          acc1[nt] = MFMA(ah, bh, acc1[nt]);
          acc1[nt] = MFMA(ah, bl, acc1[nt]);
        }
      }
    }
    if (step < 6) { VMCNT0; stage_write<CH1>(lds + ((step & 1) ? OFF_WA : OFF_WB), sr, tid); }
    __syncthreads();
  }

  // ---- L1 -> L2 transition (wave-private), overlap L2-chunk0 staging ----
  float4 s2[4];
  stage_load<CH2>(wfc + B2, s2, tid);
  bf16x8 h1h[14], h1l[14];
  transition<7>(acc1, b1p, 200, h1h, h1l, ms, lane);
  VMCNT0;
  stage_write<CH2>(lds + OFF_WA, s2, tid);
  __syncthreads();

  // ---- L2: K=14 kc, N=128 (4 nt), A=h1 hi/lo, 3 MFMA/(kc,nt) ----
  f32x16 acc2[4] = {};
  #pragma unroll
  for (int step = 0; step < 4; ++step) {
    float4 sr[4];
    if (step < 3) stage_load<CH2>(wfc + B2 + (size_t)(step+1)*CH2, sr, tid);
    const char* wb = lds + ((step & 1) ? OFF_WB : OFF_WA);
    #pragma unroll
    for (int kk = 0; kk < 4; ++kk) {
      const int kc = step*4 + kk;
      if (kc < 14) {
        #pragma unroll
        for (int nt = 0; nt < 4; ++nt) {
          const char* bp = wb + (kk*4 + nt)*2048 + lane*16;
          bf16x8 bh = *(const bf16x8*)bp;
          bf16x8 bl = *(const bf16x8*)(bp + 1024);
          acc2[nt] = MFMA(h1h[kc], bh, acc2[nt]);
          acc2[nt] = MFMA(h1h[kc], bl, acc2[nt]);
          acc2[nt] = MFMA(h1l[kc], bh, acc2[nt]);
        }
      }
    }
    if (step < 3) { VMCNT0; stage_write<CH2>(lds + ((step & 1) ? OFF_WA : OFF_WB), sr, tid); }
    __syncthreads();
  }

  // ---- L2 -> L3 ----
  float4 s3[2];
  stage_load<CH3>(wfc + B3, s3, tid);
  bf16x8 h2h[8], h2l[8];
  transition<4>(acc2, b2p, 100, h2h, h2l, ms, lane);
  VMCNT0;
  stage_write<CH3>(lds + OFF_WA, s3, tid);
  __syncthreads();

  // ---- L3: K=8 kc, N=64 (2 nt) ----
  f32x16 acc3[2] = {};
  #pragma unroll
  for (int step = 0; step < 2; ++step) {
    float4 sr[2];
    if (step < 1) stage_load<CH3>(wfc + B3 + (size_t)CH3, sr, tid);
    const char* wb = lds + ((step & 1) ? OFF_WB : OFF_WA);
    #pragma unroll
    for (int kk = 0; kk < 4; ++kk) {
      const int kc = step*4 + kk;
      #pragma unroll
      for (int nt = 0; nt < 2; ++nt) {
        const char* bp = wb + (kk*2 + nt)*2048 + lane*16;
        bf16x8 bh = *(const bf16x8*)bp;
        bf16x8 bl = *(const bf16x8*)(bp + 1024);
        acc3[nt] = MFMA(h2h[kc], bh, acc3[nt]);
        acc3[nt] = MFMA(h2h[kc], bl, acc3[nt]);
        acc3[nt] = MFMA(h2l[kc], bh, acc3[nt]);
      }
    }
    if (step < 1) { VMCNT0; stage_write<CH3>(lds + OFF_WB, sr, tid); }
    __syncthreads();
  }

  // ---- L3 -> L4 ----
  float4 s4[1];
  stage_load<CH4>(wfc + B4, s4, tid);
  bf16x8 h3h[4], h3l[4];
  transition<2>(acc3, b3p, 50, h3h, h3l, ms, lane);
  VMCNT0;
  stage_write<CH4>(lds + OFF_WA, s4, tid);
  __syncthreads();

  // ---- L4: K=4 kc, N=32 (1 nt), no relu ----
  f32x16 acc4 = {};
  {
    const char* wb = lds + OFF_WA;
    #pragma unroll
    for (int kk = 0; kk < 4; ++kk) {
      const char* bp = wb + kk*2048 + lane*16;
      bf16x8 bh = *(const bf16x8*)bp;
      bf16x8 bl = *(const bf16x8*)(bp + 1024);
      acc4 = MFMA(h3h[kk], bh, acc4);
      acc4 = MFMA(h3h[kk], bl, acc4);
      acc4 = MFMA(h3l[kk], bh, acc4);
    }
  }

  // ---- epilogue: params via wave-private f32 scratch, quantum math, store ----
  {
    float* sp = (float*)ms;   // [32][32] f32, unswizzled
    #pragma unroll
    for (int r = 0; r < 16; ++r) {
      const int row = (r & 3) + ((r >> 2) << 3) + (((lane >> 5) & 1) << 2);
      const int col = lane & 31;
      sp[row*32 + col] = acc4[r] + ((col < 10) ? b4p[col] : 0.0f);
    }
    if (lane < 16) {
      float p1[10], p2[10];
      #pragma unroll
      for (int j = 0; j < 10; ++j) {
        p1[j] = sp[(2*lane)*32 + j];
        p2[j] = sp[(2*lane + 1)*32 + j];
      }
      cpx v[4], w[4];
      build_state(p1, v);
      build_state(p2, w);
      float ir = 0.f, ii = 0.f;
      #pragma unroll
      for (int k = 0; k < 4; ++k) {
        ir += w[k].r*v[k].r + w[k].i*v[k].i;
        ii += w[k].r*v[k].i - w[k].i*v[k].r;
      }
      out[(size_t)blockIdx.x*128 + wid*16 + lane] = ir*ir + ii*ii;
    }
  }
}

extern "C" void kernel_launch(void* const* d_in, const int* in_sizes, int n_in,
                              void* d_out, int out_size, void* d_ws, size_t ws_size,
                              hipStream_t stream)
{
  const float* X  = (const float*)d_in[0];
  const float* W1 = (const float*)d_in[1];
  const float* b1 = (const float*)d_in[2];
  const float* W2 = (const float*)d_in[3];
  const float* b2 = (const float*)d_in[4];
  const float* W3 = (const float*)d_in[5];
  const float* b3 = (const float*)d_in[6];
  const float* W4 = (const float*)d_in[7];
  const float* b4 = (const float*)d_in[8];
  u16* wf = (u16*)d_ws;   // 231 blocks * 2048 B = 473088 B scratch

  prep_kernel<<<dim3(231), dim3(64), 0, stream>>>(W1, W2, W3, W4, wf);
  fused_kernel<<<dim3(512), dim3(512), 0, stream>>>(X, b1, b2, b3, b4, wf, (float*)d_out);
}